// Round 5
// baseline (511.963 us; speedup 1.0000x reference)
//
#include <hip/hip_runtime.h>
#include <stdint.h>

using bf16   = __bf16;
using bf16x4 = __attribute__((ext_vector_type(4))) __bf16;
using bf16x8 = __attribute__((ext_vector_type(8))) __bf16;
using f32x4  = __attribute__((ext_vector_type(4))) float;

#define DEPTH   11
#define NTREES  16
#define DM      256
#define PER     4095      // 2^12 - 1 nodes per tree
#define KDIM    512       // 2*DM
#define NGATES  5

__device__ __forceinline__ float sigf(float x) { return 1.0f / (1.0f + __expf(-x)); }
__device__ __forceinline__ float tanh_fast(float x) {
    float e = __expf(2.0f * x);
    return 1.0f - 2.0f / (e + 1.0f);   // safe at +/-inf
}

__device__ __forceinline__ void load_lds16(const bf16* g, bf16* l) {
    __builtin_amdgcn_global_load_lds((const __attribute__((address_space(1))) void*)g,
                                     (__attribute__((address_space(3))) void*)l,
                                     16, 0, 0);
}

// Wt[n][k] = (bf16) W[k][n];  W: [512][1280] f32 -> Wt: [1280][512] bf16.
// LDS 64x64 transpose: coalesced reads AND writes (old version did 2B stores
// at stride 1 KB = pure scatter).
__global__ __launch_bounds__(256) void prep_wt(const float* __restrict__ W,
                                               bf16* __restrict__ Wt) {
    __shared__ float tile[64][65];
    int t  = threadIdx.x;
    int kt = blockIdx.x / 20;          // 8 k-tiles
    int nt = blockIdx.x - kt * 20;     // 20 n-tiles
    int kk0 = kt << 6, n0 = nt << 6;
    int rr = t >> 6;                   // 0..3
    int cc = t & 63;
    #pragma unroll
    for (int i = 0; i < 16; ++i) {
        int kl = (rr << 4) + i;
        tile[kl][cc] = W[(size_t)(kk0 + kl) * 1280 + n0 + cc];
    }
    __syncthreads();
    #pragma unroll
    for (int i = 0; i < 16; ++i) {
        int nl = (rr << 4) + i;
        Wt[(size_t)(n0 + nl) * KDIM + kk0 + cc] = (bf16)tile[cc][nl];
    }
}

// One wave per leaf: clipped-norm embedding -> acts (f32, = d_out), actsb (bf16).
// mem for leaves is NOT written: level 1 uses zmem=1 (children mem == 0).
__global__ __launch_bounds__(256) void leaf_kernel(const int* __restrict__ tokens,
                                                   const float* __restrict__ emb,
                                                   float* acts, bf16* actsb) {
    int wid  = (blockIdx.x * 256 + threadIdx.x) >> 6;   // global leaf index 0..32767
    int lane = threadIdx.x & 63;
    int b    = wid >> 11;
    int loc  = wid & 2047;
    int id   = b * PER + loc;                           // leaf node id (off[0]==0)
    int tok  = tokens[id];

    float4 e = *reinterpret_cast<const float4*>(emb + tok * DM + lane * 4);
    float ss = e.x * e.x + e.y * e.y + e.z * e.z + e.w * e.w;
    #pragma unroll
    for (int off = 32; off; off >>= 1) ss += __shfl_xor(ss, off);
    float scale = fminf(1.0f, 1.0f / fmaxf(sqrtf(ss), 1e-7f));
    e.x *= scale; e.y *= scale; e.z *= scale; e.w *= scale;

    int o = id * DM + lane * 4;
    *reinterpret_cast<float4*>(acts + o) = e;
    bf16x4 eb;
    eb.x = (bf16)e.x; eb.y = (bf16)e.y; eb.z = (bf16)e.z; eb.w = (bf16)e.w;
    *reinterpret_cast<bf16x4*>(actsb + o) = eb;
}

// ---------- LDS-staged big-level kernel (levels 1-4, Mt >= 128) ----------
// Block: 256 thr (4 waves, 2x2), output tile 128 rows x (32 ucols x 5 gates).
// LDS: A [kblk8][row128][8] bf16 (16 KB), B [kblk8][col160][8] bf16 (20 KB).
__global__ __launch_bounds__(256) void level_big(
        const bf16* __restrict__ actsb_in, const bf16* __restrict__ Wt,
        const float* __restrict__ bias, float* __restrict__ mem,
        float* __restrict__ acts, bf16* __restrict__ actsb_out,
        int off_k, int off_km1, int zmem) {
    __shared__ __align__(16) bf16 ldsA[8][128][8];
    __shared__ __align__(16) bf16 ldsB[8][160][8];

    int t    = threadIdx.x;
    int lane = t & 63;
    int w    = t >> 6;
    int lo   = lane & 15;
    int hi   = lane >> 4;          // 0..3
    int wr   = w >> 1;             // row half (64 rows)
    int wu   = w & 1;              // ucol half (16 ucols)

    int rt   = blockIdx.x >> 3;    // row tile (128 rows within tree)
    int uct  = blockIdx.x & 7;     // ucol tile (32 of 256)
    int b    = blockIdx.y;         // tree

    int rm  = rt << 7;
    int uc0 = uct << 5;

    const bf16* Abase = actsb_in + (size_t)(b * PER + off_km1) * DM;

    const bf16* aSrc[4];
    #pragma unroll
    for (int i = 0; i < 4; ++i) {
        int s   = i * 256 + t;
        aSrc[i] = Abase + (size_t)(rm + (s & 127)) * KDIM + (s >> 7) * 8;
    }
    const bf16* bSrc[5];
    #pragma unroll
    for (int i = 0; i < 5; ++i) {
        int s   = i * 256 + t;
        int kb  = s / 160;
        int col = s - kb * 160;
        int g   = col >> 5;
        int c   = col & 31;
        bSrc[i] = Wt + (size_t)(g * DM + uc0 + c) * KDIM + kb * 8;
    }

    bf16* ldsAf = &ldsA[0][0][0];
    bf16* ldsBf = &ldsB[0][0][0];

    f32x4 acc[NGATES][4] = {};

    for (int kt = 0; kt < 8; ++kt) {
        int ko = kt * 64;
        #pragma unroll
        for (int i = 0; i < 4; ++i)
            load_lds16(aSrc[i] + ko, ldsAf + (i * 256 + t) * 8);
        #pragma unroll
        for (int i = 0; i < 5; ++i)
            load_lds16(bSrc[i] + ko, ldsBf + (i * 256 + t) * 8);
        __syncthreads();

        #pragma unroll
        for (int q = 0; q < 2; ++q) {
            bf16x8 af[4];
            #pragma unroll
            for (int rg = 0; rg < 4; ++rg)
                af[rg] = *reinterpret_cast<const bf16x8*>(&ldsA[q * 4 + hi][wr * 64 + rg * 16 + lo][0]);
            #pragma unroll
            for (int g = 0; g < NGATES; ++g) {
                bf16x8 bb = *reinterpret_cast<const bf16x8*>(&ldsB[q * 4 + hi][g * 32 + wu * 16 + lo][0]);
                #pragma unroll
                for (int rg = 0; rg < 4; ++rg)
                    acc[g][rg] = __builtin_amdgcn_mfma_f32_16x16x32_bf16(af[rg], bb, acc[g][rg], 0, 0, 0);
            }
        }
        __syncthreads();
    }

    int ucol = uc0 + wu * 16 + lo;
    float bi[NGATES];
    #pragma unroll
    for (int g = 0; g < NGATES; ++g) bi[g] = bias[g * DM + ucol];

    int treebase = b * PER;
    #pragma unroll
    for (int rg = 0; rg < 4; ++rg) {
        #pragma unroll
        for (int r = 0; r < 4; ++r) {
            int ml = rm + wr * 64 + rg * 16 + (hi << 2) + r;
            int id = treebase + off_k + ml;
            float cl = 0.0f, cr = 0.0f;
            if (!zmem) {
                int ch = (treebase + off_km1 + (ml << 1)) * DM + ucol;
                cl = mem[ch];
                cr = mem[ch + DM];
            }
            float gi = acc[0][rg][r] + bi[0];
            float gl = acc[1][rg][r] + bi[1];
            float gr = acc[2][rg][r] + bi[2];
            float go = acc[3][rg][r] + bi[3];
            float gu = acc[4][rg][r] + bi[4];
            float c  = sigf(gi) * tanh_fast(gu) + sigf(gl) * cl + sigf(gr) * cr;
            float h  = sigf(go) * tanh_fast(c);
            int oi = id * DM + ucol;
            acts[oi]      = h;
            mem[oi]       = c;
            actsb_out[oi] = (bf16)h;
        }
    }
}

// ---------- Per-tree tail (levels 5-11): one block per tree ----------
// Block = 512 thr (8 waves). Per level each wave owns ucol-tiles jt = w, w+8
// (16 ucols x 5 gates each) and sweeps all NRT row-groups with B reused in
// registers (acc[5][NRT]). Only __syncthreads() between levels — the block
// covers the whole tree, no device-scope sync needed.
template<int NRT>
__device__ void tail_level(bf16* __restrict__ actsb, const bf16* __restrict__ Wt,
                           const float* __restrict__ bias, float* __restrict__ mem,
                           float* __restrict__ acts,
                           int tb, int off_km1, int Mt, int w, int lo, int hi) {
    int off_k = off_km1 + (Mt << 1);
    int mask  = Mt - 1;
    const bf16* Af = actsb + (size_t)(tb + off_km1) * DM;   // A row m at +m*512

    for (int jt = w; jt < 16; jt += 8) {
        int ucol = (jt << 4) + lo;
        const bf16* bptr = Wt + (size_t)ucol * KDIM + hi * 8;
        const bf16* aptr[NRT];
        #pragma unroll
        for (int rg = 0; rg < NRT; ++rg) {
            int rA = ((rg << 4) + lo) & mask;    // wraps (duplicates) when Mt<16
            aptr[rg] = Af + (rA << 1) * DM + hi * 8;
        }

        f32x4 acc[NGATES][NRT] = {};
        #pragma unroll
        for (int kt = 0; kt < KDIM / 32; ++kt) {
            bf16x8 a[NRT];
            #pragma unroll
            for (int rg = 0; rg < NRT; ++rg)
                a[rg] = *reinterpret_cast<const bf16x8*>(aptr[rg] + kt * 32);
            #pragma unroll
            for (int g = 0; g < NGATES; ++g) {
                bf16x8 bb = *reinterpret_cast<const bf16x8*>(bptr + (size_t)g * (DM * KDIM) + kt * 32);
                #pragma unroll
                for (int rg = 0; rg < NRT; ++rg)
                    acc[g][rg] = __builtin_amdgcn_mfma_f32_16x16x32_bf16(a[rg], bb, acc[g][rg], 0, 0, 0);
            }
        }

        float bi[NGATES];
        #pragma unroll
        for (int g = 0; g < NGATES; ++g) bi[g] = bias[g * DM + ucol];

        #pragma unroll
        for (int rg = 0; rg < NRT; ++rg) {
            #pragma unroll
            for (int r = 0; r < 4; ++r) {
                int m = (rg << 4) + (hi << 2) + r;
                if (m < Mt) {                         // no-op when Mt >= 16
                    int id = tb + off_k + m;
                    int ch = (tb + off_km1 + (m << 1)) * DM + ucol;
                    float cl = mem[ch];
                    float cr = mem[ch + DM];
                    float gi = acc[0][rg][r] + bi[0];
                    float gl = acc[1][rg][r] + bi[1];
                    float gr = acc[2][rg][r] + bi[2];
                    float go = acc[3][rg][r] + bi[3];
                    float gu = acc[4][rg][r] + bi[4];
                    float c  = sigf(gi) * tanh_fast(gu) + sigf(gl) * cl + sigf(gr) * cr;
                    float h  = sigf(go) * tanh_fast(c);
                    int oi = id * DM + ucol;
                    acts[oi]  = h;
                    mem[oi]   = c;
                    actsb[oi] = (bf16)h;
                }
            }
        }
    }
}

__global__ __launch_bounds__(512) void tree_tail(bf16* actsb, const bf16* __restrict__ Wt,
                                                 const float* __restrict__ bias,
                                                 float* mem, float* acts) {
    int tb   = blockIdx.x * PER;       // one block per tree
    int t    = threadIdx.x;
    int lane = t & 63;
    int w    = t >> 6;
    int lo   = lane & 15;
    int hi   = lane >> 4;
    // offsets: off[4]=3840, then 3968, 4032, 4064, 4080, 4088, 4092 (root=4094)
    tail_level<4>(actsb, Wt, bias, mem, acts, tb, 3840, 64, w, lo, hi); __syncthreads();
    tail_level<2>(actsb, Wt, bias, mem, acts, tb, 3968, 32, w, lo, hi); __syncthreads();
    tail_level<1>(actsb, Wt, bias, mem, acts, tb, 4032, 16, w, lo, hi); __syncthreads();
    tail_level<1>(actsb, Wt, bias, mem, acts, tb, 4064,  8, w, lo, hi); __syncthreads();
    tail_level<1>(actsb, Wt, bias, mem, acts, tb, 4080,  4, w, lo, hi); __syncthreads();
    tail_level<1>(actsb, Wt, bias, mem, acts, tb, 4088,  2, w, lo, hi); __syncthreads();
    tail_level<1>(actsb, Wt, bias, mem, acts, tb, 4092,  1, w, lo, hi);
}

extern "C" void kernel_launch(void* const* d_in, const int* in_sizes, int n_in,
                              void* d_out, int out_size, void* d_ws, size_t ws_size,
                              hipStream_t stream) {
    (void)in_sizes; (void)n_in; (void)out_size; (void)ws_size;
    const int*   tokens = (const int*)d_in[0];
    const float* emb    = (const float*)d_in[8];
    const float* W      = (const float*)d_in[9];
    const float* bias   = (const float*)d_in[10];
    float* acts = (float*)d_out;

    char* ws = (char*)d_ws;
    bf16*  Wt    = (bf16*)ws;                               // 1,310,720 B
    bf16*  actsb = (bf16*)(ws + 1310720);                   // 33,546,240 B
    float* mem   = (float*)(ws + 1310720 + 33546240);       // 67,092,480 B

    prep_wt<<<dim3(160), dim3(256), 0, stream>>>(W, Wt);
    leaf_kernel<<<dim3(8192), dim3(256), 0, stream>>>(tokens, emb, acts, actsb);

    int off_km1 = 0;
    for (int k = 1; k <= 4; ++k) {
        int shift = DEPTH - k;
        int Mt    = 1 << shift;              // 1024, 512, 256, 128
        int off_k = off_km1 + (Mt << 1);
        level_big<<<dim3((Mt >> 7) * 8, NTREES), dim3(256), 0, stream>>>(
            actsb, Wt, bias, mem, acts, actsb, off_k, off_km1, (k == 1) ? 1 : 0);
        off_km1 = off_k;
    }
    // levels 5..11: one block per tree, block-local barriers only
    tree_tail<<<dim3(NTREES), dim3(512), 0, stream>>>(actsb, Wt, bias, mem, acts);
}

// Round 6
// 248.287 us; speedup vs baseline: 2.0620x; 2.0620x over previous
//
#include <hip/hip_runtime.h>
#include <stdint.h>

using bf16   = __bf16;
using bf16x4 = __attribute__((ext_vector_type(4))) __bf16;
using bf16x8 = __attribute__((ext_vector_type(8))) __bf16;
using f32x4  = __attribute__((ext_vector_type(4))) float;

#define DEPTH   11
#define NTREES  16
#define DM      256
#define PER     4095      // 2^12 - 1 nodes per tree
#define KDIM    512       // 2*DM
#define NGATES  5

__device__ __forceinline__ float sigf(float x) { return 1.0f / (1.0f + __expf(-x)); }
__device__ __forceinline__ float tanh_fast(float x) {
    float e = __expf(2.0f * x);
    return 1.0f - 2.0f / (e + 1.0f);   // safe at +/-inf
}

__device__ __forceinline__ void load_lds16(const bf16* g, bf16* l) {
    __builtin_amdgcn_global_load_lds((const __attribute__((address_space(1))) void*)g,
                                     (__attribute__((address_space(3))) void*)l,
                                     16, 0, 0);
}

// Wt[n][k] = (bf16) W[k][n];  W: [512][1280] f32 -> Wt: [1280][512] bf16.
// LDS 64x64 transpose: coalesced reads AND writes.
__global__ __launch_bounds__(256) void prep_wt(const float* __restrict__ W,
                                               bf16* __restrict__ Wt) {
    __shared__ float tile[64][65];
    int t  = threadIdx.x;
    int kt = blockIdx.x / 20;          // 8 k-tiles
    int nt = blockIdx.x - kt * 20;     // 20 n-tiles
    int kk0 = kt << 6, n0 = nt << 6;
    int rr = t >> 6;                   // 0..3
    int cc = t & 63;
    #pragma unroll
    for (int i = 0; i < 16; ++i) {
        int kl = (rr << 4) + i;
        tile[kl][cc] = W[(size_t)(kk0 + kl) * 1280 + n0 + cc];
    }
    __syncthreads();
    #pragma unroll
    for (int i = 0; i < 16; ++i) {
        int nl = (rr << 4) + i;
        Wt[(size_t)(n0 + nl) * KDIM + kk0 + cc] = (bf16)tile[cc][nl];
    }
}

// One wave per leaf: clipped-norm embedding -> acts (f32, = d_out), actsb (bf16).
// mem for leaves is NOT written: level 1 uses zmem=1 (children mem == 0).
__global__ __launch_bounds__(256) void leaf_kernel(const int* __restrict__ tokens,
                                                   const float* __restrict__ emb,
                                                   float* acts, bf16* actsb) {
    int wid  = (blockIdx.x * 256 + threadIdx.x) >> 6;   // global leaf index 0..32767
    int lane = threadIdx.x & 63;
    int b    = wid >> 11;
    int loc  = wid & 2047;
    int id   = b * PER + loc;                           // leaf node id (off[0]==0)
    int tok  = tokens[id];

    float4 e = *reinterpret_cast<const float4*>(emb + tok * DM + lane * 4);
    float ss = e.x * e.x + e.y * e.y + e.z * e.z + e.w * e.w;
    #pragma unroll
    for (int off = 32; off; off >>= 1) ss += __shfl_xor(ss, off);
    float scale = fminf(1.0f, 1.0f / fmaxf(sqrtf(ss), 1e-7f));
    e.x *= scale; e.y *= scale; e.z *= scale; e.w *= scale;

    int o = id * DM + lane * 4;
    *reinterpret_cast<float4*>(acts + o) = e;
    bf16x4 eb;
    eb.x = (bf16)e.x; eb.y = (bf16)e.y; eb.z = (bf16)e.z; eb.w = (bf16)e.w;
    *reinterpret_cast<bf16x4*>(actsb + o) = eb;
}

// ---------- LDS-staged big-level kernel (levels 1-4, Mt >= 128) ----------
// Block: 256 thr (4 waves, 2x2), output tile 128 rows x (32 ucols x 5 gates).
// DOUBLE-BUFFERED (T3 minimum 2-phase): LDS A[2][8][128][8] + B[2][8][160][8]
// = 72 KB. Per K-step: issue STAGE(next) -> compute(cur) -> one syncthreads
// (its vmcnt(0) drain lands AFTER the 40-MFMA compute phase = overlap).
__global__ __launch_bounds__(256) void level_big(
        const bf16* __restrict__ actsb_in, const bf16* __restrict__ Wt,
        const float* __restrict__ bias, float* __restrict__ mem,
        float* __restrict__ acts, bf16* __restrict__ actsb_out,
        int off_k, int off_km1, int zmem) {
    __shared__ __align__(16) bf16 ldsA[2][8][128][8];
    __shared__ __align__(16) bf16 ldsB[2][8][160][8];

    int t    = threadIdx.x;
    int lane = t & 63;
    int w    = t >> 6;
    int lo   = lane & 15;
    int hi   = lane >> 4;          // 0..3
    int wr   = w >> 1;             // row half (64 rows)
    int wu   = w & 1;              // ucol half (16 ucols)

    int rt   = blockIdx.x >> 3;    // row tile (128 rows within tree)
    int uct  = blockIdx.x & 7;     // ucol tile (32 of 256)
    int b    = blockIdx.y;         // tree

    int rm  = rt << 7;
    int uc0 = uct << 5;

    const bf16* Abase = actsb_in + (size_t)(b * PER + off_km1) * DM;

    const bf16* aSrc[4];
    #pragma unroll
    for (int i = 0; i < 4; ++i) {
        int s   = i * 256 + t;
        aSrc[i] = Abase + (size_t)(rm + (s & 127)) * KDIM + (s >> 7) * 8;
    }
    const bf16* bSrc[5];
    #pragma unroll
    for (int i = 0; i < 5; ++i) {
        int s   = i * 256 + t;
        int kb  = s / 160;
        int col = s - kb * 160;
        int g   = col >> 5;
        int c   = col & 31;
        bSrc[i] = Wt + (size_t)(g * DM + uc0 + c) * KDIM + kb * 8;
    }

    // bias loads hoisted: complete long before the epilogue needs them
    int ucol = uc0 + wu * 16 + lo;
    float bi[NGATES];
    #pragma unroll
    for (int g = 0; g < NGATES; ++g) bi[g] = bias[g * DM + ucol];

    // prologue stage into buf 0
    #pragma unroll
    for (int i = 0; i < 4; ++i)
        load_lds16(aSrc[i], &ldsA[0][0][0][0] + (i * 256 + t) * 8);
    #pragma unroll
    for (int i = 0; i < 5; ++i)
        load_lds16(bSrc[i], &ldsB[0][0][0][0] + (i * 256 + t) * 8);

    f32x4 acc[NGATES][4] = {};

    __syncthreads();   // drain prologue stage (vmcnt0 + barrier)

    for (int kt = 0; kt < 8; ++kt) {
        int cur = kt & 1;
        if (kt < 7) {                              // prefetch next K-tile
            int ko  = (kt + 1) * 64;
            int nxt = cur ^ 1;
            #pragma unroll
            for (int i = 0; i < 4; ++i)
                load_lds16(aSrc[i] + ko, &ldsA[nxt][0][0][0] + (i * 256 + t) * 8);
            #pragma unroll
            for (int i = 0; i < 5; ++i)
                load_lds16(bSrc[i] + ko, &ldsB[nxt][0][0][0] + (i * 256 + t) * 8);
        }

        #pragma unroll
        for (int q = 0; q < 2; ++q) {
            bf16x8 af[4];
            #pragma unroll
            for (int rg = 0; rg < 4; ++rg)
                af[rg] = *reinterpret_cast<const bf16x8*>(&ldsA[cur][q * 4 + hi][wr * 64 + rg * 16 + lo][0]);
            #pragma unroll
            for (int g = 0; g < NGATES; ++g) {
                bf16x8 bb = *reinterpret_cast<const bf16x8*>(&ldsB[cur][q * 4 + hi][g * 32 + wu * 16 + lo][0]);
                #pragma unroll
                for (int rg = 0; rg < 4; ++rg)
                    acc[g][rg] = __builtin_amdgcn_mfma_f32_16x16x32_bf16(af[rg], bb, acc[g][rg], 0, 0, 0);
            }
        }
        __syncthreads();   // drains prefetch (overlapped with compute) + barrier
    }

    int treebase = b * PER;
    #pragma unroll
    for (int rg = 0; rg < 4; ++rg) {
        #pragma unroll
        for (int r = 0; r < 4; ++r) {
            int ml = rm + wr * 64 + rg * 16 + (hi << 2) + r;
            int id = treebase + off_k + ml;
            float cl = 0.0f, cr = 0.0f;
            if (!zmem) {
                int ch = (treebase + off_km1 + (ml << 1)) * DM + ucol;
                cl = mem[ch];
                cr = mem[ch + DM];
            }
            float gi = acc[0][rg][r] + bi[0];
            float gl = acc[1][rg][r] + bi[1];
            float gr = acc[2][rg][r] + bi[2];
            float go = acc[3][rg][r] + bi[3];
            float gu = acc[4][rg][r] + bi[4];
            float c  = sigf(gi) * tanh_fast(gu) + sigf(gl) * cl + sigf(gr) * cr;
            float h  = sigf(go) * tanh_fast(c);
            int oi = id * DM + ucol;
            acts[oi]      = h;
            mem[oi]       = c;
            actsb_out[oi] = (bf16)h;
        }
    }
}

// ---------- Small-level kernel (levels 5-11): full (row-tile, ucol-tile) split
// One wave per 16 rows x 16 ucols x 5 gates; grid = M_total/4 blocks x 4 waves.
// Col-split divides Wt traffic across blocks; per-level dispatch = the sync.
__global__ __launch_bounds__(256) void level_kernel(
        const bf16* __restrict__ actsb_in, const bf16* __restrict__ Wt,
        const float* __restrict__ bias, float* mem, float* acts, bf16* actsb_out,
        int off_k, int off_km1, int shift) {
    int wid  = blockIdx.x * 4 + (threadIdx.x >> 6);
    int lane = threadIdx.x & 63;
    int tile = wid >> 4;
    int uc   = wid & 15;
    int m0   = tile << 4;
    int lo   = lane & 15;
    int hi   = lane >> 4;
    int mask = (1 << shift) - 1;

    int mA   = m0 + lo;
    int rowA = (mA >> shift) * PER + off_km1 + ((mA & mask) << 1);
    const bf16* aptr = actsb_in + rowA * DM + hi * 8;

    int ucol = (uc << 4) + lo;
    const bf16* bptr = Wt + ucol * KDIM + hi * 8;

    f32x4 acc[NGATES] = {};

    #pragma unroll
    for (int kt = 0; kt < KDIM / 32; ++kt) {
        bf16x8 a = *reinterpret_cast<const bf16x8*>(aptr + kt * 32);
        #pragma unroll
        for (int g = 0; g < NGATES; ++g) {
            bf16x8 bb = *reinterpret_cast<const bf16x8*>(bptr + g * (DM * KDIM) + kt * 32);
            acc[g] = __builtin_amdgcn_mfma_f32_16x16x32_bf16(a, bb, acc[g], 0, 0, 0);
        }
    }

    float bi[NGATES];
    #pragma unroll
    for (int g = 0; g < NGATES; ++g) bi[g] = bias[g * DM + ucol];

    #pragma unroll
    for (int r = 0; r < 4; ++r) {
        int m   = m0 + (hi << 2) + r;
        int tb  = (m >> shift) * PER;
        int loc = m & mask;
        int id  = tb + off_k + loc;
        int ch  = (tb + off_km1 + (loc << 1)) * DM + ucol;
        float cl = mem[ch];
        float cr = mem[ch + DM];
        float gi = acc[0][r] + bi[0];
        float gl = acc[1][r] + bi[1];
        float gr = acc[2][r] + bi[2];
        float go = acc[3][r] + bi[3];
        float gu = acc[4][r] + bi[4];
        float c  = sigf(gi) * tanh_fast(gu) + sigf(gl) * cl + sigf(gr) * cr;
        float h  = sigf(go) * tanh_fast(c);
        int oi = id * DM + ucol;
        acts[oi]      = h;
        mem[oi]       = c;
        actsb_out[oi] = (bf16)h;
    }
}

extern "C" void kernel_launch(void* const* d_in, const int* in_sizes, int n_in,
                              void* d_out, int out_size, void* d_ws, size_t ws_size,
                              hipStream_t stream) {
    (void)in_sizes; (void)n_in; (void)out_size; (void)ws_size;
    const int*   tokens = (const int*)d_in[0];
    const float* emb    = (const float*)d_in[8];
    const float* W      = (const float*)d_in[9];
    const float* bias   = (const float*)d_in[10];
    float* acts = (float*)d_out;

    char* ws = (char*)d_ws;
    bf16*  Wt    = (bf16*)ws;                               // 1,310,720 B
    bf16*  actsb = (bf16*)(ws + 1310720);                   // 33,546,240 B
    float* mem   = (float*)(ws + 1310720 + 33546240);       // 67,092,480 B

    prep_wt<<<dim3(160), dim3(256), 0, stream>>>(W, Wt);
    leaf_kernel<<<dim3(8192), dim3(256), 0, stream>>>(tokens, emb, acts, actsb);

    int off_km1 = 0;
    for (int k = 1; k <= DEPTH; ++k) {
        int shift   = DEPTH - k;
        int Mt      = 1 << shift;            // rows per tree at this level
        int off_k   = off_km1 + (Mt << 1);
        int M_total = NTREES << shift;
        if (Mt >= 128) {
            level_big<<<dim3((Mt >> 7) * 8, NTREES), dim3(256), 0, stream>>>(
                actsb, Wt, bias, mem, acts, actsb, off_k, off_km1, (k == 1) ? 1 : 0);
        } else {
            level_kernel<<<dim3(M_total / 4), dim3(256), 0, stream>>>(
                actsb, Wt, bias, mem, acts, actsb, off_k, off_km1, shift);
        }
        off_km1 = off_k;
    }
}

// Round 7
// 191.701 us; speedup vs baseline: 2.6706x; 1.2952x over previous
//
#include <hip/hip_runtime.h>
#include <stdint.h>

using bf16   = __bf16;
using bf16x4 = __attribute__((ext_vector_type(4))) __bf16;
using bf16x8 = __attribute__((ext_vector_type(8))) __bf16;
using f32x4  = __attribute__((ext_vector_type(4))) float;

#define DEPTH   11
#define NTREES  16
#define DM      256
#define PER     4095      // 2^12 - 1 nodes per tree
#define KDIM    512       // 2*DM
#define NGATES  5

__device__ __forceinline__ float sigf(float x) { return 1.0f / (1.0f + __expf(-x)); }
__device__ __forceinline__ float tanh_fast(float x) {
    float e = __expf(2.0f * x);
    return 1.0f - 2.0f / (e + 1.0f);   // safe at +/-inf
}

__device__ __forceinline__ void load_lds16(const bf16* g, bf16* l) {
    __builtin_amdgcn_global_load_lds((const __attribute__((address_space(1))) void*)g,
                                     (__attribute__((address_space(3))) void*)l,
                                     16, 0, 0);
}

// Wfrag: W repacked in MFMA-B-fragment order. Fragment f = gt*16 + ks
// (gt = col-tile of 16, ks = k-slice of 32) is 512 bf16 contiguous; lane l,
// elem e holds W[ks*32 + (l>>4)*8 + e][gt*16 + (l&15)]. A wave's b128 load of
// one fragment is perfectly coalesced (lane l reads bytes [f*1024+l*16, +16)).
__global__ __launch_bounds__(256) void prep_wfrag(const float* __restrict__ W,
                                                  bf16* __restrict__ Wf) {
    int tid = blockIdx.x * 256 + threadIdx.x;       // 0 .. 81919
    int f   = tid >> 6;                             // fragment id 0..1279
    int l   = tid & 63;
    int gt  = f >> 4;
    int ks  = f & 15;
    int n   = (gt << 4) + (l & 15);
    int k0  = (ks << 5) + ((l >> 4) << 3);
    bf16x8 v;
    #pragma unroll
    for (int e = 0; e < 8; ++e) v[e] = (bf16)W[(size_t)(k0 + e) * 1280 + n];
    *reinterpret_cast<bf16x8*>(Wf + (size_t)tid * 8) = v;
}

// One wave per leaf: clipped-norm embedding -> acts (f32, = d_out), actsb (bf16).
// mem for leaves is NOT written: level 1 uses zmem=1 (children mem == 0).
__global__ __launch_bounds__(256) void leaf_kernel(const int* __restrict__ tokens,
                                                   const float* __restrict__ emb,
                                                   float* acts, bf16* actsb) {
    int wid  = (blockIdx.x * 256 + threadIdx.x) >> 6;   // global leaf index 0..32767
    int lane = threadIdx.x & 63;
    int b    = wid >> 11;
    int loc  = wid & 2047;
    int id   = b * PER + loc;                           // leaf node id (off[0]==0)
    int tok  = tokens[id];

    float4 e = *reinterpret_cast<const float4*>(emb + tok * DM + lane * 4);
    float ss = e.x * e.x + e.y * e.y + e.z * e.z + e.w * e.w;
    #pragma unroll
    for (int off = 32; off; off >>= 1) ss += __shfl_xor(ss, off);
    float scale = fminf(1.0f, 1.0f / fmaxf(sqrtf(ss), 1e-7f));
    e.x *= scale; e.y *= scale; e.z *= scale; e.w *= scale;

    int o = id * DM + lane * 4;
    *reinterpret_cast<float4*>(acts + o) = e;
    bf16x4 eb;
    eb.x = (bf16)e.x; eb.y = (bf16)e.y; eb.z = (bf16)e.z; eb.w = (bf16)e.w;
    *reinterpret_cast<bf16x4*>(actsb + o) = eb;
}

// ---------- Big-level kernel: A via LDS (dbuf), B direct Wfrag->reg ----------
// Block: 256 thr (4 waves). Tile: RPB rows x 64 ucols (x 5 gates).
// Each wave: all RPB rows x its own 16 ucols x 5 gates; acc[5][RPB/16].
// LDS: A only, [2][8][RPB][8] bf16 (2*RPB*128 B). B loads are coalesced
// b128 from Wfrag (L2-resident), on the VMEM pipe parallel to LDS reads.
template<int RPB>
__global__ __launch_bounds__(256, 2) void level_big(
        const bf16* __restrict__ actsb_in, const bf16* __restrict__ Wfrag,
        const float* __restrict__ bias, float* __restrict__ mem,
        float* __restrict__ acts, bf16* __restrict__ actsb_out,
        int off_k, int off_km1, int zmem) {
    constexpr int NRG = RPB / 16;          // row groups per wave
    constexpr int NLD = RPB / 32;          // global_load_lds issues per K-step
    __shared__ __align__(16) bf16 ldsA[2][8][RPB][8];

    int t    = threadIdx.x;
    int lane = t & 63;
    int w    = t >> 6;
    int lo   = lane & 15;
    int hi   = lane >> 4;          // 0..3

    int rt    = blockIdx.x >> 2;   // row tile within tree
    int uct   = blockIdx.x & 3;    // ucol tile (64 of 256)
    int b     = blockIdx.y;        // tree
    int rm    = rt * RPB;
    int wslot = (uct << 2) + w;    // 0..15: this wave's 16-ucol slot

    const bf16* Abase = actsb_in + (size_t)(b * PER + off_km1) * DM;

    // A staging sources: slot s = i*256+t -> row = s & (RPB-1), kblk = s >> log2(RPB)
    const bf16* aSrc[NLD];
    #pragma unroll
    for (int i = 0; i < NLD; ++i) {
        int s   = i * 256 + t;
        aSrc[i] = Abase + (size_t)(rm + (s & (RPB - 1))) * KDIM + (s / RPB) * 8;
    }

    // B fragment base for this wave: gate g, kslice ks at + ((g<<8 | ks) << 9)
    const bf16* bbase = Wfrag + ((size_t)wslot << 13) + lane * 8;

    int ucol = (wslot << 4) + lo;
    float bi[NGATES];
    #pragma unroll
    for (int g = 0; g < NGATES; ++g) bi[g] = bias[g * DM + ucol];

    // prologue: stage K-tile 0 into buf 0
    #pragma unroll
    for (int i = 0; i < NLD; ++i)
        load_lds16(aSrc[i], &ldsA[0][0][0][0] + (i * 256 + t) * 8);

    f32x4 acc[NGATES][NRG] = {};

    __syncthreads();

    for (int kt = 0; kt < 8; ++kt) {
        int cur = kt & 1;
        if (kt < 7) {                              // prefetch next K-tile
            int ko = (kt + 1) * 64;
            #pragma unroll
            for (int i = 0; i < NLD; ++i)
                load_lds16(aSrc[i] + ko, &ldsA[cur ^ 1][0][0][0] + (i * 256 + t) * 8);
        }

        #pragma unroll
        for (int q = 0; q < 2; ++q) {
            bf16x8 bb[NGATES];
            #pragma unroll
            for (int g = 0; g < NGATES; ++g)
                bb[g] = *reinterpret_cast<const bf16x8*>(bbase + (size_t)(((g << 8) + (kt << 1) + q) << 9));
            #pragma unroll
            for (int rg = 0; rg < NRG; ++rg) {
                bf16x8 af = *reinterpret_cast<const bf16x8*>(&ldsA[cur][(q << 2) + hi][(rg << 4) + lo][0]);
                #pragma unroll
                for (int g = 0; g < NGATES; ++g)
                    acc[g][rg] = __builtin_amdgcn_mfma_f32_16x16x32_bf16(af, bb[g], acc[g][rg], 0, 0, 0);
            }
        }
        __syncthreads();   // drains prefetch (overlapped w/ compute) + protects buf
    }

    int treebase = b * PER;
    #pragma unroll
    for (int rg = 0; rg < NRG; ++rg) {
        #pragma unroll
        for (int r = 0; r < 4; ++r) {
            int ml = rm + (rg << 4) + (hi << 2) + r;
            int id = treebase + off_k + ml;
            float cl = 0.0f, cr = 0.0f;
            if (!zmem) {
                int ch = (treebase + off_km1 + (ml << 1)) * DM + ucol;
                cl = mem[ch];
                cr = mem[ch + DM];
            }
            float gi = acc[0][rg][r] + bi[0];
            float gl = acc[1][rg][r] + bi[1];
            float gr = acc[2][rg][r] + bi[2];
            float go = acc[3][rg][r] + bi[3];
            float gu = acc[4][rg][r] + bi[4];
            float c  = sigf(gi) * tanh_fast(gu) + sigf(gl) * cl + sigf(gr) * cr;
            float h  = sigf(go) * tanh_fast(c);
            int oi = id * DM + ucol;
            acts[oi]      = h;
            mem[oi]       = c;
            actsb_out[oi] = (bf16)h;
        }
    }
}

// ---------- Small-level kernel (levels 5-11): B from Wfrag (coalesced) ----
// One wave per 16 rows x 16 ucols x 5 gates; grid = M_total/4 blocks x 4 waves.
__global__ __launch_bounds__(256) void level_kernel(
        const bf16* __restrict__ actsb_in, const bf16* __restrict__ Wfrag,
        const float* __restrict__ bias, float* mem, float* acts, bf16* actsb_out,
        int off_k, int off_km1, int shift) {
    int wid  = blockIdx.x * 4 + (threadIdx.x >> 6);
    int lane = threadIdx.x & 63;
    int tile = wid >> 4;
    int uc   = wid & 15;
    int m0   = tile << 4;
    int lo   = lane & 15;
    int hi   = lane >> 4;
    int mask = (1 << shift) - 1;

    int mA   = m0 + lo;
    int rowA = (mA >> shift) * PER + off_km1 + ((mA & mask) << 1);
    const bf16* aptr = actsb_in + (size_t)rowA * DM + hi * 8;

    // B fragments: gate g, kslice kt at Wfrag + ((g*256 + uc*16 + kt) << 9)
    const bf16* bbase = Wfrag + ((size_t)uc << 13) + lane * 8;

    int ucol = (uc << 4) + lo;
    float bi[NGATES];
    #pragma unroll
    for (int g = 0; g < NGATES; ++g) bi[g] = bias[g * DM + ucol];

    f32x4 acc[NGATES] = {};

    #pragma unroll
    for (int kt = 0; kt < KDIM / 32; ++kt) {
        bf16x8 a = *reinterpret_cast<const bf16x8*>(aptr + kt * 32);
        #pragma unroll
        for (int g = 0; g < NGATES; ++g) {
            bf16x8 bb = *reinterpret_cast<const bf16x8*>(bbase + (size_t)(((g << 8) + kt) << 9));
            acc[g] = __builtin_amdgcn_mfma_f32_16x16x32_bf16(a, bb, acc[g], 0, 0, 0);
        }
    }

    #pragma unroll
    for (int r = 0; r < 4; ++r) {
        int m   = m0 + (hi << 2) + r;
        int tb  = (m >> shift) * PER;
        int loc = m & mask;
        int id  = tb + off_k + loc;
        int ch  = (tb + off_km1 + (loc << 1)) * DM + ucol;
        float cl = mem[ch];
        float cr = mem[ch + DM];
        float gi = acc[0][r] + bi[0];
        float gl = acc[1][r] + bi[1];
        float gr = acc[2][r] + bi[2];
        float go = acc[3][r] + bi[3];
        float gu = acc[4][r] + bi[4];
        float c  = sigf(gi) * tanh_fast(gu) + sigf(gl) * cl + sigf(gr) * cr;
        float h  = sigf(go) * tanh_fast(c);
        int oi = id * DM + ucol;
        acts[oi]      = h;
        mem[oi]       = c;
        actsb_out[oi] = (bf16)h;
    }
}

extern "C" void kernel_launch(void* const* d_in, const int* in_sizes, int n_in,
                              void* d_out, int out_size, void* d_ws, size_t ws_size,
                              hipStream_t stream) {
    (void)in_sizes; (void)n_in; (void)out_size; (void)ws_size;
    const int*   tokens = (const int*)d_in[0];
    const float* emb    = (const float*)d_in[8];
    const float* W      = (const float*)d_in[9];
    const float* bias   = (const float*)d_in[10];
    float* acts = (float*)d_out;

    char* ws = (char*)d_ws;
    bf16*  Wfrag = (bf16*)ws;                               // 1,310,720 B
    bf16*  actsb = (bf16*)(ws + 1310720);                   // 33,546,240 B
    float* mem   = (float*)(ws + 1310720 + 33546240);       // 67,092,480 B

    prep_wfrag<<<dim3(320), dim3(256), 0, stream>>>(W, Wfrag);
    leaf_kernel<<<dim3(8192), dim3(256), 0, stream>>>(tokens, emb, acts, actsb);

    int off_km1 = 0;
    for (int k = 1; k <= DEPTH; ++k) {
        int shift   = DEPTH - k;
        int Mt      = 1 << shift;            // rows per tree at this level
        int off_k   = off_km1 + (Mt << 1);
        int M_total = NTREES << shift;
        if (Mt >= 512) {
            level_big<128><<<dim3((Mt / 128) * 4, NTREES), dim3(256), 0, stream>>>(
                actsb, Wfrag, bias, mem, acts, actsb, off_k, off_km1, (k == 1) ? 1 : 0);
        } else if (Mt >= 128) {
            level_big<64><<<dim3((Mt / 64) * 4, NTREES), dim3(256), 0, stream>>>(
                actsb, Wfrag, bias, mem, acts, actsb, off_k, off_km1, 0);
        } else {
            level_kernel<<<dim3(M_total / 4), dim3(256), 0, stream>>>(
                actsb, Wfrag, bias, mem, acts, actsb, off_k, off_km1, shift);
        }
        off_km1 = off_k;
    }
}

// Round 10
// 184.528 us; speedup vs baseline: 2.7744x; 1.0389x over previous
//
#include <hip/hip_runtime.h>
#include <stdint.h>

using bf16   = __bf16;
using bf16x4 = __attribute__((ext_vector_type(4))) __bf16;
using bf16x8 = __attribute__((ext_vector_type(8))) __bf16;
using f32x4  = __attribute__((ext_vector_type(4))) float;

#define DEPTH   11
#define NTREES  16
#define DM      256
#define PER     4095      // 2^12 - 1 nodes per tree
#define KDIM    512       // 2*DM
#define NGATES  5

__device__ __forceinline__ float sigf(float x) { return 1.0f / (1.0f + __expf(-x)); }
__device__ __forceinline__ float tanh_fast(float x) {
    float e = __expf(2.0f * x);
    return 1.0f - 2.0f / (e + 1.0f);   // safe at +/-inf
}

__device__ __forceinline__ void load_lds16(const bf16* g, bf16* l) {
    __builtin_amdgcn_global_load_lds((const __attribute__((address_space(1))) void*)g,
                                     (__attribute__((address_space(3))) void*)l,
                                     16, 0, 0);
}

// Wfrag: W repacked in MFMA-B-fragment order. Fragment f = gt*16 + ks
// (gt = col-tile of 16 over 1280 cols, ks = k-slice of 32) is 512 bf16
// contiguous; lane l elem e holds W[ks*32 + (l>>4)*8 + e][gt*16 + (l&15)].
__global__ __launch_bounds__(256) void prep_wfrag(const float* __restrict__ W,
                                                  bf16* __restrict__ Wf) {
    int tid = blockIdx.x * 256 + threadIdx.x;       // 0 .. 81919
    int f   = tid >> 6;                             // fragment id 0..1279
    int l   = tid & 63;
    int gt  = f >> 4;
    int ks  = f & 15;
    int n   = (gt << 4) + (l & 15);
    int k0  = (ks << 5) + ((l >> 4) << 3);
    bf16x8 v;
    #pragma unroll
    for (int e = 0; e < 8; ++e) v[e] = (bf16)W[(size_t)(k0 + e) * 1280 + n];
    *reinterpret_cast<bf16x8*>(Wf + (size_t)tid * 8) = v;
}

// One wave per leaf: clipped-norm embedding -> acts (f32, = d_out), actsb (bf16).
// mem for leaves is NOT written: level 1 uses zmem=1 (children mem == 0).
__global__ __launch_bounds__(256) void leaf_kernel(const int* __restrict__ tokens,
                                                   const float* __restrict__ emb,
                                                   float* acts, bf16* actsb) {
    int wid  = (blockIdx.x * 256 + threadIdx.x) >> 6;   // global leaf index 0..32767
    int lane = threadIdx.x & 63;
    int b    = wid >> 11;
    int loc  = wid & 2047;
    int id   = b * PER + loc;                           // leaf node id (off[0]==0)
    int tok  = tokens[id];

    float4 e = *reinterpret_cast<const float4*>(emb + tok * DM + lane * 4);
    float ss = e.x * e.x + e.y * e.y + e.z * e.z + e.w * e.w;
    #pragma unroll
    for (int off = 32; off; off >>= 1) ss += __shfl_xor(ss, off);
    float scale = fminf(1.0f, 1.0f / fmaxf(sqrtf(ss), 1e-7f));
    e.x *= scale; e.y *= scale; e.z *= scale; e.w *= scale;

    int o = id * DM + lane * 4;
    *reinterpret_cast<float4*>(acts + o) = e;
    bf16x4 eb;
    eb.x = (bf16)e.x; eb.y = (bf16)e.y; eb.z = (bf16)e.z; eb.w = (bf16)e.w;
    *reinterpret_cast<bf16x4*>(actsb + o) = eb;
}

// ---------- Big-level kernel (Mt >= 128): counted-vmcnt pipeline (T4) ----
// Block: 256 thr (4 waves). Tile: 64 rows x 64 ucols (x 5 gates).
// Wave: 64 rows x 16 ucols x 5 gates; acc[5][4] (80 VGPR), B regs dbuf (80).
// Per K-step: issue {2 global_load_lds (A,kt+1), 10 B-reg loads (kt+1)} ->
// compute(kt) -> s_waitcnt vmcnt(10) (A staged; B STAYS IN FLIGHT across
// the barrier) -> s_barrier. No vmcnt(0) drain in the main loop.
__global__ __launch_bounds__(256, 2) void level_big(
        const bf16* __restrict__ actsb_in, const bf16* __restrict__ Wfrag,
        const float* __restrict__ bias, float* __restrict__ mem,
        float* __restrict__ acts, bf16* __restrict__ actsb_out,
        int off_k, int off_km1, int zmem) {
    constexpr int RPB = 64;
    constexpr int NRG = RPB / 16;          // 4 row groups per wave
    constexpr int NLD = RPB / 32;          // 2 global_load_lds per K-step
    __shared__ __align__(16) bf16 ldsA[2][8][RPB][8];

    int t    = threadIdx.x;
    int lane = t & 63;
    int w    = t >> 6;
    int lo   = lane & 15;
    int hi   = lane >> 4;          // 0..3

    int rt    = blockIdx.x >> 2;   // row tile within tree
    int uct   = blockIdx.x & 3;    // ucol tile (64 of 256)
    int b     = blockIdx.y;        // tree
    int rm    = rt * RPB;
    int wslot = (uct << 2) + w;    // 0..15: this wave's 16-ucol slot

    const bf16* Abase = actsb_in + (size_t)(b * PER + off_km1) * DM;

    // A staging: slot s = i*256+t -> row = s&63, kblk = s>>6 (linear LDS dest)
    const bf16* aSrc[NLD];
    #pragma unroll
    for (int i = 0; i < NLD; ++i) {
        int s   = i * 256 + t;
        aSrc[i] = Abase + (size_t)(rm + (s & (RPB - 1))) * KDIM + (s / RPB) * 8;
    }

    // B fragment base; gate g, kslice ks at + (((g<<8)|ks) << 9) elems
    const bf16* bbase = Wfrag + ((size_t)wslot << 13) + lane * 8;

    int ucol = (wslot << 4) + lo;
    float bi[NGATES];
    #pragma unroll
    for (int g = 0; g < NGATES; ++g) bi[g] = bias[g * DM + ucol];

    // ---- prologue: stage K-tile 0 (LDS) + load B(kt=0) into regs ----
    #pragma unroll
    for (int i = 0; i < NLD; ++i)
        load_lds16(aSrc[i], &ldsA[0][0][0][0] + (i * 256 + t) * 8);
    bf16x8 bb[2][NGATES][2];
    #pragma unroll
    for (int g = 0; g < NGATES; ++g)
        #pragma unroll
        for (int q = 0; q < 2; ++q)
            bb[0][g][q] = *reinterpret_cast<const bf16x8*>(bbase + (size_t)(((g << 8) | q) << 9));

    f32x4 acc[NGATES][NRG] = {};

    __builtin_amdgcn_sched_barrier(0);
    asm volatile("s_waitcnt vmcnt(10)" ::: "memory");   // A staged; B may fly
    __builtin_amdgcn_sched_barrier(0);
    __builtin_amdgcn_s_barrier();
    __builtin_amdgcn_sched_barrier(0);

    #pragma unroll
    for (int kt = 0; kt < 8; ++kt) {
        int cur = kt & 1;
        if (kt < 7) {                              // issue next K-tile's loads
            int ko = (kt + 1) * 64;
            #pragma unroll
            for (int i = 0; i < NLD; ++i)
                load_lds16(aSrc[i] + ko, &ldsA[cur ^ 1][0][0][0] + (i * 256 + t) * 8);
            #pragma unroll
            for (int g = 0; g < NGATES; ++g)
                #pragma unroll
                for (int q = 0; q < 2; ++q)
                    bb[cur ^ 1][g][q] = *reinterpret_cast<const bf16x8*>(
                        bbase + (size_t)(((g << 8) | ((kt + 1) * 2 + q)) << 9));
        }
        __builtin_amdgcn_sched_barrier(0);

        #pragma unroll
        for (int q = 0; q < 2; ++q) {
            #pragma unroll
            for (int rg = 0; rg < NRG; ++rg) {
                bf16x8 af = *reinterpret_cast<const bf16x8*>(&ldsA[cur][(q << 2) + hi][(rg << 4) + lo][0]);
                #pragma unroll
                for (int g = 0; g < NGATES; ++g)
                    acc[g][rg] = __builtin_amdgcn_mfma_f32_16x16x32_bf16(af, bb[cur][g][q], acc[g][rg], 0, 0, 0);
            }
        }
        __builtin_amdgcn_sched_barrier(0);

        if (kt < 7) {
            asm volatile("s_waitcnt vmcnt(10)" ::: "memory");  // drain A stages only
            __builtin_amdgcn_sched_barrier(0);
            __builtin_amdgcn_s_barrier();
            __builtin_amdgcn_sched_barrier(0);
        }
    }

    int treebase = b * PER;
    #pragma unroll
    for (int rg = 0; rg < NRG; ++rg) {
        #pragma unroll
        for (int r = 0; r < 4; ++r) {
            int ml = rm + (rg << 4) + (hi << 2) + r;
            int id = treebase + off_k + ml;
            float cl = 0.0f, cr = 0.0f;
            if (!zmem) {
                int ch = (treebase + off_km1 + (ml << 1)) * DM + ucol;
                cl = mem[ch];
                cr = mem[ch + DM];
            }
            float gi = acc[0][rg][r] + bi[0];
            float gl = acc[1][rg][r] + bi[1];
            float gr = acc[2][rg][r] + bi[2];
            float go = acc[3][rg][r] + bi[3];
            float gu = acc[4][rg][r] + bi[4];
            float c  = sigf(gi) * tanh_fast(gu) + sigf(gl) * cl + sigf(gr) * cr;
            float h  = sigf(go) * tanh_fast(c);
            int oi = id * DM + ucol;
            acts[oi]      = h;
            mem[oi]       = c;
            actsb_out[oi] = (bf16)h;
        }
    }
}

// ---------- Small-level kernel (levels with Mt < 128): B from Wfrag ----
// One wave per 16 rows x 16 ucols x 5 gates; grid = M_total/4 blocks x 4 waves.
__global__ __launch_bounds__(256) void level_kernel(
        const bf16* __restrict__ actsb_in, const bf16* __restrict__ Wfrag,
        const float* __restrict__ bias, float* mem, float* acts, bf16* actsb_out,
        int off_k, int off_km1, int shift) {
    int wid  = blockIdx.x * 4 + (threadIdx.x >> 6);
    int lane = threadIdx.x & 63;
    int tile = wid >> 4;
    int uc   = wid & 15;
    int m0   = tile << 4;
    int lo   = lane & 15;
    int hi   = lane >> 4;
    int mask = (1 << shift) - 1;

    int mA   = m0 + lo;
    int rowA = (mA >> shift) * PER + off_km1 + ((mA & mask) << 1);
    const bf16* aptr = actsb_in + (size_t)rowA * DM + hi * 8;

    const bf16* bbase = Wfrag + ((size_t)uc << 13) + lane * 8;

    int ucol = (uc << 4) + lo;
    float bi[NGATES];
    #pragma unroll
    for (int g = 0; g < NGATES; ++g) bi[g] = bias[g * DM + ucol];

    f32x4 acc[NGATES] = {};

    #pragma unroll
    for (int kt = 0; kt < KDIM / 32; ++kt) {
        bf16x8 a = *reinterpret_cast<const bf16x8*>(aptr + kt * 32);
        #pragma unroll
        for (int g = 0; g < NGATES; ++g) {
            bf16x8 bb = *reinterpret_cast<const bf16x8*>(bbase + (size_t)(((g << 8) + kt) << 9));
            acc[g] = __builtin_amdgcn_mfma_f32_16x16x32_bf16(a, bb, acc[g], 0, 0, 0);
        }
    }

    #pragma unroll
    for (int r = 0; r < 4; ++r) {
        int m   = m0 + (hi << 2) + r;
        int tb  = (m >> shift) * PER;
        int loc = m & mask;
        int id  = tb + off_k + loc;
        int ch  = (tb + off_km1 + (loc << 1)) * DM + ucol;
        float cl = mem[ch];
        float cr = mem[ch + DM];
        float gi = acc[0][r] + bi[0];
        float gl = acc[1][r] + bi[1];
        float gr = acc[2][r] + bi[2];
        float go = acc[3][r] + bi[3];
        float gu = acc[4][r] + bi[4];
        float c  = sigf(gi) * tanh_fast(gu) + sigf(gl) * cl + sigf(gr) * cr;
        float h  = sigf(go) * tanh_fast(c);
        int oi = id * DM + ucol;
        acts[oi]      = h;
        mem[oi]       = c;
        actsb_out[oi] = (bf16)h;
    }
}

extern "C" void kernel_launch(void* const* d_in, const int* in_sizes, int n_in,
                              void* d_out, int out_size, void* d_ws, size_t ws_size,
                              hipStream_t stream) {
    (void)in_sizes; (void)n_in; (void)out_size; (void)ws_size;
    const int*   tokens = (const int*)d_in[0];
    const float* emb    = (const float*)d_in[8];
    const float* W      = (const float*)d_in[9];
    const float* bias   = (const float*)d_in[10];
    float* acts = (float*)d_out;

    char* ws = (char*)d_ws;
    bf16*  Wfrag = (bf16*)ws;                               // 1,310,720 B
    bf16*  actsb = (bf16*)(ws + 1310720);                   // 33,546,240 B
    float* mem   = (float*)(ws + 1310720 + 33546240);       // 67,092,480 B

    prep_wfrag<<<dim3(320), dim3(256), 0, stream>>>(W, Wfrag);
    leaf_kernel<<<dim3(8192), dim3(256), 0, stream>>>(tokens, emb, acts, actsb);

    int off_km1 = 0;
    for (int k = 1; k <= DEPTH; ++k) {
        int shift   = DEPTH - k;
        int Mt      = 1 << shift;            // rows per tree at this level
        int off_k   = off_km1 + (Mt << 1);
        int M_total = NTREES << shift;
        if (Mt >= 128) {
            level_big<<<dim3((Mt / 64) * 4, NTREES), dim3(256), 0, stream>>>(
                actsb, Wfrag, bias, mem, acts, actsb, off_k, off_km1, (k == 1) ? 1 : 0);
        } else {
            level_kernel<<<dim3(M_total / 4), dim3(256), 0, stream>>>(
                actsb, Wfrag, bias, mem, acts, actsb, off_k, off_km1, shift);
        }
        off_km1 = off_k;
    }
}